// Round 7
// baseline (2368.094 us; speedup 1.0000x reference)
//
#include <hip/hip_runtime.h>

typedef __bf16 bf16_t;
typedef __bf16 bf16x8 __attribute__((ext_vector_type(8)));
typedef float floatx4 __attribute__((ext_vector_type(4)));

#define MFMA16(a, b, c) __builtin_amdgcn_mfma_f32_16x16x32_bf16(a, b, c, 0, 0, 0)

#define AS1 __attribute__((address_space(1)))
#define AS3 __attribute__((address_space(3)))

// async 16B global -> LDS (lane i lands at ldsbase + i*16; ldsbase wave-uniform)
__device__ __forceinline__ void gload_lds16(const bf16_t* g, bf16_t* l) {
    __builtin_amdgcn_global_load_lds((const AS1 unsigned int*)g,
                                     (AS3 unsigned int*)l, 16, 0, 0);
}

struct TPtrs { const void* src[5]; bf16_t* dst[5]; };
struct GPtrs { const bf16_t* Bt[4]; bf16_t* C[4]; };

// ---------------------------------------------------------------------------
// Detect input dtype on-device (flag=1 -> bf16 inputs; measured: fp32 world).
// ---------------------------------------------------------------------------
__global__ __launch_bounds__(256) void detect_dtype_kernel(const unsigned int* W,
                                                           int* flag) {
    int tid = threadIdx.x;
    int cnt = 0;
    for (int i = tid; i < 4096; i += 256) {
        unsigned int fb = (W[i] & 0xFFFFu) << 16;
        float v = __uint_as_float(fb);
        float a = fabsf(v);
        if (a > 1e-5f && a < 4.f) cnt++;
    }
    __shared__ int s[256];
    s[tid] = cnt;
    __syncthreads();
    for (int st = 128; st > 0; st >>= 1) {
        if (tid < st) s[tid] += s[tid + st];
        __syncthreads();
    }
    if (tid == 0) *flag = (s[0] > 2048) ? 1 : 0;
}

// ---------------------------------------------------------------------------
// Fused prep: z<5 -> transpose weight z (2048x2048 -> bf16, dst[n][k]);
// z==5 -> canonicalize x -> bf16 (8,388,608 elems).  grid (32,32,6).
// ---------------------------------------------------------------------------
__global__ __launch_bounds__(256) void prep_kernel(TPtrs p,
                                                   const void* __restrict__ xsrc,
                                                   bf16_t* __restrict__ xb,
                                                   const int* __restrict__ flag) {
    int z = blockIdx.z;
    int tid = threadIdx.x;
    int isbf = *flag;
    if (z == 5) {
        size_t blin = (size_t)blockIdx.y * 32 + blockIdx.x;   // [0,1024)
        size_t i0 = (blin * 256 + tid) * 8;
#pragma unroll
        for (int l = 0; l < 4; ++l) {
            size_t idx = i0 + (size_t)l * 2097152;            // 1024*256*8
            bf16x8 o;
            if (isbf) {
                o = *(const bf16x8*)((const bf16_t*)xsrc + idx);
            } else {
                const float* s = (const float*)xsrc + idx;
                float4 a = *(const float4*)s;
                float4 b = *(const float4*)(s + 4);
                o[0] = (bf16_t)a.x; o[1] = (bf16_t)a.y; o[2] = (bf16_t)a.z; o[3] = (bf16_t)a.w;
                o[4] = (bf16_t)b.x; o[5] = (bf16_t)b.y; o[6] = (bf16_t)b.z; o[7] = (bf16_t)b.w;
            }
            *(bf16x8*)(xb + idx) = o;
        }
        return;
    }
    __shared__ bf16_t tile[64][72];  // +8 pad
    bf16_t* dst = p.dst[z];
    int bx = blockIdx.x, by = blockIdx.y;
#pragma unroll
    for (int l = 0; l < 2; ++l) {
        int idx = tid + 256 * l;          // 512 x 8 elems = 64 rows x 64 cols
        int r = idx >> 3, c8 = (idx & 7) * 8;
        bf16x8 o;
        if (isbf) {
            const bf16_t* src = (const bf16_t*)p.src[z];
            o = *(const bf16x8*)&src[(size_t)(by * 64 + r) * 2048 + bx * 64 + c8];
        } else {
            const float* src = (const float*)p.src[z];
            const float* sp = &src[(size_t)(by * 64 + r) * 2048 + bx * 64 + c8];
            float4 a = *(const float4*)sp;
            float4 b = *(const float4*)(sp + 4);
            o[0] = (bf16_t)a.x; o[1] = (bf16_t)a.y; o[2] = (bf16_t)a.z; o[3] = (bf16_t)a.w;
            o[4] = (bf16_t)b.x; o[5] = (bf16_t)b.y; o[6] = (bf16_t)b.z; o[7] = (bf16_t)b.w;
        }
        *(bf16x8*)&tile[r][c8] = o;
    }
    __syncthreads();
#pragma unroll
    for (int l = 0; l < 2; ++l) {
        int idx = tid + 256 * l;
        int r = idx >> 3, c8 = (idx & 7) * 8;
        bf16x8 o;
#pragma unroll
        for (int m = 0; m < 8; ++m) o[m] = tile[c8 + m][r];
        *(bf16x8*)&dst[(size_t)(bx * 64 + r) * 2048 + by * 64 + c8] = o;
    }
}

// ---------------------------------------------------------------------------
// QKVG GEMM with fused RoPE.  C[M,N] = A[M,K] @ Bt[N,K]^T, bf16 out.
// 256x256 tile, 512 threads (8 waves 2x4), BK=32.
//
// ROUND-7: OCCUPANCY over ring depth.  Rounds 3-6 proved that at 1
// block/CU (128 KiB LDS, 2 waves/SIMD lockstep) no intra-wave schedule
// makes the LDS and matrix pipes overlap (all variants = pipes summed,
// MfmaUtil 40-43%).  m114/m97: the overlap mechanism at this class is
// cross-WAVE TLP from multiple resident blocks.  So: ring 4 -> 2
// (LDS 64 KiB), __launch_bounds__(512,4) -> 2 blocks/CU (grid 512 =
// 2 x 256 CUs exactly), 4 waves/SIMD.  Round-3 skeleton otherwise:
// one barrier + one wait per tile, reg-prefetch of next-tile frags.
//
// Staging distance 1: A(t+1) at phase-A top, B(t+1) at phase-B top;
// mid-tile wait = vmcnt(0) lgkmcnt(0) (drain window spans a 16-MFMA
// phase shared by 4 waves; the co-resident block covers residue).
// Ledger (ring-2, dist-1): frags(t) reads issue after barrier(mid t-1),
// drain at mid-t lgkmcnt(0) before barrier(mid t); buf[t&1] overwritten
// at top of t+1 (A) / phase-B of t+1 (B), both after barrier(mid t).
// b23(t) issues top-t, drains mid-t, buffer overwritten phase-B of t+1.
// No region ever staged with pending reads.  Per-wave vmcnt(0) before
// the barrier makes all waves' stages visible after it.
// ---------------------------------------------------------------------------
__global__ __launch_bounds__(512, 4) void gemm_bt(const bf16_t* __restrict__ A,
                                                  GPtrs p, int K) {
    __shared__ bf16_t sm[2][2][8192];   // [buf][A/B][256*32] = 64 KiB
    int z = blockIdx.z;
    bf16_t* __restrict__ C = p.C[z];
    const int N = 2048;
    int tid = threadIdx.x, lane = tid & 63, wid = tid >> 6;
    int l15 = lane & 15, quad = lane >> 4;
    int wm = wid >> 2, wn = wid & 3;                 // 2 x 4 waves
    int m0 = blockIdx.y * 256, n0 = blockIdx.x * 256;

    // staging: wave wid covers rows [wid*16,+16) of each 128-row half;
    // inverse XOR on the SOURCE k-granule so swizzled reads recover data.
    int kg = ((lane & 3) ^ ((lane >> 3) & 3)) * 8;
    size_t aoff = (size_t)(wid * 16 + (lane >> 2)) * K + kg;
    const bf16_t* Au = A + (size_t)m0 * K;           // uniform base
    const bf16_t* Bu = p.Bt[z] + (size_t)n0 * K;

    // fragment read swizzle: granule = quad ^ ((row>>1)&3), row = R0+l15.
    int gph = (quad ^ ((l15 >> 1) & 3)) * 8;

    // B-fragment rows: pair rotary cols (d, d+64) of one head into adjacent j
    int jr[4];
#pragma unroll
    for (int j = 0; j < 4; ++j)
        jr[j] = (wn >> 1) * 128 + (j & 1) * 64 + (wn & 1) * 32 + (j >> 1) * 16 + l15;

    const int NT = K >> 5;                           // 32-wide K tiles (64)

    // ---- prologue: stage tile 0 (4 loads); drain; barrier; read frags(0)
    {
        const bf16_t* sa = Au + aoff;
        const bf16_t* sb = Bu + aoff;
        bf16_t* da = &sm[0][0][wid * 512];
        bf16_t* db = &sm[0][1][wid * 512];
        gload_lds16(sa, da);
        gload_lds16(sa + (size_t)128 * K, da + 4096);
        gload_lds16(sb, db);
        gload_lds16(sb + (size_t)128 * K, db + 4096);
    }
    asm volatile("s_waitcnt vmcnt(0)" ::: "memory");
    __builtin_amdgcn_s_barrier();
    asm volatile("" ::: "memory");

    bf16x8 afA[8], afB[8], b01[2], b23[2];
    floatx4 acc[8][4] = {};

    // initial fragment reads: af(0) -> afA, b01(0)
    {
        const bf16_t* bA0 = &sm[0][0][0];
        const bf16_t* bB0 = &sm[0][1][0];
#pragma unroll
        for (int i = 0; i < 8; ++i)
            afA[i] = *(const bf16x8*)&bA0[(wm * 128 + i * 16 + l15) * 32 + gph];
        b01[0] = *(const bf16x8*)&bB0[jr[0] * 32 + gph];
        b01[1] = *(const bf16x8*)&bB0[jr[1] * 32 + gph];
    }

#define TILE_STEP(T, AFU, AFL)                                                 \
    {                                                                          \
        const int t_ = (T);                                                    \
        const bf16_t* bB_ = &sm[t_ & 1][1][0];                                 \
        /* ---- phase A: stage A(t+1) | read b23(t) | MFMA j01 */              \
        if (t_ + 1 < NT) {                                                     \
            const bf16_t* s_ = Au + (size_t)(t_ + 1) * 32 + aoff;              \
            bf16_t* d_ = &sm[(t_ + 1) & 1][0][wid * 512];                      \
            gload_lds16(s_, d_);                                               \
            gload_lds16(s_ + (size_t)128 * K, d_ + 4096);                      \
        }                                                                      \
        b23[0] = *(const bf16x8*)&bB_[jr[2] * 32 + gph];                       \
        b23[1] = *(const bf16x8*)&bB_[jr[3] * 32 + gph];                       \
        __builtin_amdgcn_s_setprio(1);                                         \
        _Pragma("unroll")                                                      \
        for (int i = 0; i < 8; ++i) {                                          \
            acc[i][0] = MFMA16(AFU[i], b01[0], acc[i][0]);                     \
            acc[i][1] = MFMA16(AFU[i], b01[1], acc[i][1]);                     \
        }                                                                      \
        __builtin_amdgcn_s_setprio(0);                                         \
        /* ---- phase B: stage B(t+1) | drain+barrier | prefetch frags(t+1) */ \
        /*      | MFMA j23 (prefetch drains under it) */                       \
        if (t_ + 1 < NT) {                                                     \
            const bf16_t* s_ = Bu + (size_t)(t_ + 1) * 32 + aoff;              \
            bf16_t* d_ = &sm[(t_ + 1) & 1][1][wid * 512];                      \
            gload_lds16(s_, d_);                                               \
            gload_lds16(s_ + (size_t)128 * K, d_ + 4096);                      \
        }                                                                      \
        asm volatile("s_waitcnt vmcnt(0) lgkmcnt(0)" ::: "memory");            \
        __builtin_amdgcn_s_barrier();                                          \
        asm volatile("" ::: "memory");                                         \
        if (t_ + 1 < NT) {                                                     \
            const bf16_t* nA_ = &sm[(t_ + 1) & 1][0][0];                       \
            const bf16_t* nB_ = &sm[(t_ + 1) & 1][1][0];                       \
            _Pragma("unroll")                                                  \
            for (int i = 0; i < 8; ++i)                                        \
                AFL[i] = *(const bf16x8*)&nA_[(wm * 128 + i * 16 + l15) * 32 + gph]; \
            b01[0] = *(const bf16x8*)&nB_[jr[0] * 32 + gph];                   \
            b01[1] = *(const bf16x8*)&nB_[jr[1] * 32 + gph];                   \
        }                                                                      \
        __builtin_amdgcn_s_setprio(1);                                         \
        _Pragma("unroll")                                                      \
        for (int i = 0; i < 8; ++i) {                                          \
            acc[i][2] = MFMA16(AFU[i], b23[0], acc[i][2]);                     \
            acc[i][3] = MFMA16(AFU[i], b23[1], acc[i][3]);                     \
        }                                                                      \
        __builtin_amdgcn_s_setprio(0);                                         \
    }

    for (int it = 0; it < NT; it += 2) {
        TILE_STEP(it, afA, afB)
        TILE_STEP(it + 1, afB, afA)
    }
#undef TILE_STEP

    if (z < 2) {
        // ---- fused RoPE epilogue (q: scaled, k: unscaled)
        float scale = (z == 0) ? 0.08838834764831845f : 1.0f;
#pragma unroll
        for (int jj = 0; jj < 2; ++jj) {
            int d = (wn & 1) * 32 + jj * 16 + l15;               // head-local [0,64)
            float inv = exp2f(-(float)d * (13.287712379549449f / 64.f));
            int cb = n0 + (wn >> 1) * 128 + d;                   // x1 column
#pragma unroll
            for (int i = 0; i < 8; ++i)
#pragma unroll
                for (int r = 0; r < 4; ++r) {
                    int row = m0 + wm * 128 + i * 16 + quad * 4 + r;
                    float ang = (float)(row & 2047) * inv;
                    float sn, cs;
                    __sincosf(ang, &sn, &cs);
                    float x1 = acc[i][2 * jj][r], x2 = acc[i][2 * jj + 1][r];
                    size_t ro = (size_t)row * N + cb;
                    C[ro]      = (bf16_t)((x1 * cs - x2 * sn) * scale);
                    C[ro + 64] = (bf16_t)((x2 * cs + x1 * sn) * scale);
                }
        }
    } else {
#pragma unroll
        for (int i = 0; i < 8; ++i)
#pragma unroll
            for (int j = 0; j < 4; ++j)
#pragma unroll
                for (int r = 0; r < 4; ++r) {
                    int row = m0 + wm * 128 + i * 16 + quad * 4 + r;
                    int col = n0 + jr[j];
                    C[(size_t)row * N + col] = (bf16_t)acc[i][j][r];
                }
    }
}

// ---------------------------------------------------------------------------
// Final GEMM: out dtype dynamic (flag=1 -> bf16, else fp32).  saddr staging.
// ---------------------------------------------------------------------------
__global__ __launch_bounds__(256) void gemm_bt_dyn(const bf16_t* __restrict__ A,
                                                   const bf16_t* __restrict__ Bt,
                                                   void* __restrict__ C, int K,
                                                   const int* __restrict__ flag) {
    __shared__ bf16_t sA[128 * 64];
    __shared__ bf16_t sB[128 * 64];
    const int N = 2048;
    int tid = threadIdx.x, lane = tid & 63, wid = tid >> 6;
    int l15 = lane & 15, quad = lane >> 4;
    int wm = wid >> 1, wn = wid & 1;
    int m0 = blockIdx.y * 128, n0 = blockIdx.x * 128;
    int isbf = *flag;

    int srow = tid >> 3;
    unsigned aoff = (unsigned)(srow * K + (((tid & 7) ^ (srow & 7)) * 8));
    const bf16_t* Au = A + (size_t)m0 * K;
    const bf16_t* Bu = Bt + (size_t)n0 * K;
    bf16_t* la = &sA[(size_t)(wid * 64) * 8];
    bf16_t* lb = &sB[(size_t)(wid * 64) * 8];
    const int rstep = 32 * K;
    int x7 = l15 & 7;

    floatx4 acc[4][4] = {};
    for (int kk = 0; kk < K; kk += 64) {
#pragma unroll
        for (int l = 0; l < 4; ++l)
            gload_lds16(Au + l * rstep + aoff, la + l * 2048);
#pragma unroll
        for (int l = 0; l < 4; ++l)
            gload_lds16(Bu + l * rstep + aoff, lb + l * 2048);
        Au += 64;
        Bu += 64;
        __syncthreads();
#pragma unroll
        for (int k2 = 0; k2 < 2; ++k2) {
            int koff = ((k2 * 4 + quad) ^ x7) * 8;
            bf16x8 af[4], bfv[4];
#pragma unroll
            for (int i = 0; i < 4; ++i)
                af[i] = *(const bf16x8*)&sA[(wm * 64 + i * 16 + l15) * 64 + koff];
#pragma unroll
            for (int j = 0; j < 4; ++j)
                bfv[j] = *(const bf16x8*)&sB[(wn * 64 + j * 16 + l15) * 64 + koff];
#pragma unroll
            for (int i = 0; i < 4; ++i)
#pragma unroll
                for (int j = 0; j < 4; ++j)
                    acc[i][j] = MFMA16(af[i], bfv[j], acc[i][j]);
        }
        __syncthreads();
    }
#pragma unroll
    for (int i = 0; i < 4; ++i)
#pragma unroll
        for (int j = 0; j < 4; ++j)
#pragma unroll
            for (int r = 0; r < 4; ++r) {
                int row = m0 + wm * 64 + i * 16 + quad * 4 + r;
                int col = n0 + wn * 64 + j * 16 + l15;
                if (isbf) ((bf16_t*)C)[(size_t)row * N + col] = (bf16_t)acc[i][j][r];
                else      ((float*)C)[(size_t)row * N + col] = acc[i][j][r];
            }
}

// ---------------------------------------------------------------------------
// Pass A: Ut[e][d] = sum_t v[t][e] * gamma^(63-t) * k[t][d].  grid 1024.
// Column-chunk XOR swizzle on transposed staging (conflict-reduced).
// ---------------------------------------------------------------------------
__global__ __launch_bounds__(256) void chunk_state_kernel(const bf16_t* __restrict__ Kc,
                                                          const bf16_t* __restrict__ Vc,
                                                          bf16_t* __restrict__ U) {
    __shared__ bf16_t sKT[128 * 72];
    __shared__ bf16_t sVT[128 * 72];
    int bx = blockIdx.x;
    int n = bx & 31, h = (bx >> 5) & 15, b = bx >> 9;
    int tid = threadIdx.x, lane = tid & 63, wid = tid >> 6;
    int l15 = lane & 15, quad = lane >> 4;
    int wm = wid >> 1, wn = wid & 1;
    float log2g = log2f(1.f - exp2f(-5.f - (float)h));

#pragma unroll
    for (int l = 0; l < 4; ++l) {
        int idx = tid + 256 * l;          // 1024 = 64 rows x 16 vec8
        int t = idx >> 4, k = idx & 15, d8 = k * 8;
        size_t gb = (((size_t)((b * 2048 + n * 64 + t) * 16 + h)) << 7) + d8;
        bf16x8 kv = *(const bf16x8*)&Kc[gb];
        bf16x8 vv = *(const bf16x8*)&Vc[gb];
        float kdec = exp2f((float)(63 - t) * log2g);
        int swc = (((t >> 3) ^ (k & 7)) * 8) + (t & 7);
#pragma unroll
        for (int m = 0; m < 8; ++m) {
            sKT[(d8 + m) * 72 + swc] = (bf16_t)((float)kv[m] * kdec);
            sVT[(d8 + m) * 72 + swc] = vv[m];
        }
    }
    __syncthreads();

    floatx4 acc[4][4] = {};
#pragma unroll
    for (int k2 = 0; k2 < 2; ++k2) {
        int q = k2 * 4 + quad;
        bf16x8 af[4], bfv[4];
#pragma unroll
        for (int i = 0; i < 4; ++i) {
            int key = (2 * i + (l15 >> 3)) & 7;
            af[i] = *(const bf16x8*)&sVT[(wm * 64 + i * 16 + l15) * 72 + (q ^ key) * 8];
        }
#pragma unroll
        for (int j = 0; j < 4; ++j) {
            int key = (2 * j + (l15 >> 3)) & 7;
            bfv[j] = *(const bf16x8*)&sKT[(wn * 64 + j * 16 + l15) * 72 + (q ^ key) * 8];
        }
#pragma unroll
        for (int i = 0; i < 4; ++i)
#pragma unroll
            for (int j = 0; j < 4; ++j) acc[i][j] = MFMA16(af[i], bfv[j], acc[i][j]);
    }
    size_t ub = (size_t)bx * 16384;
#pragma unroll
    for (int i = 0; i < 4; ++i)
#pragma unroll
        for (int j = 0; j < 4; ++j)
#pragma unroll
            for (int r = 0; r < 4; ++r) {
                int e = wm * 64 + i * 16 + quad * 4 + r;
                int d = wn * 64 + j * 16 + l15;
                U[ub + (size_t)e * 128 + d] = (bf16_t)acc[i][j][r];
            }
}

// ---------------------------------------------------------------------------
// Pass B: in-place scan  St[n] = state before chunk n (transposed layout).
// ---------------------------------------------------------------------------
__global__ __launch_bounds__(256) void scan_kernel(bf16_t* __restrict__ US) {
    int bx = blockIdx.x;
    int bh = bx >> 3, slice = bx & 7;
    int h = bh & 15;
    float log2g = log2f(1.f - exp2f(-5.f - (float)h));
    float gC = exp2f(64.f * log2g);
    size_t base = (size_t)bh * 32 * 16384 + (size_t)slice * 2048 + (size_t)threadIdx.x * 8;
    float acc[8] = {};
#pragma unroll 4
    for (int n = 0; n < 32; ++n) {
        size_t o = base + (size_t)n * 16384;
        bf16x8 u = *(const bf16x8*)&US[o];
        bf16x8 s;
#pragma unroll
        for (int m = 0; m < 8; ++m) s[m] = (bf16_t)acc[m];
        *(bf16x8*)&US[o] = s;
#pragma unroll
        for (int m = 0; m < 8; ++m) acc[m] = gC * acc[m] + (float)u[m];
    }
}

// ---------------------------------------------------------------------------
// Pass C: chunk output + gated RMSNorm.  grid 1024.
// sQ/sK: [64][128] chunk XOR swizzle key (t&7); sVT: [128][72] swizzled;
// sA overlays sK (dead after phase 1) -> ~51 KB LDS -> 3 blocks/CU.
// ---------------------------------------------------------------------------
__global__ __launch_bounds__(256) void chunk_out_kernel(
    const bf16_t* __restrict__ Q, const bf16_t* __restrict__ Kc,
    const bf16_t* __restrict__ Vc, const bf16_t* __restrict__ G,
    const void* __restrict__ gwp, const bf16_t* __restrict__ St,
    bf16_t* __restrict__ OG, const int* __restrict__ flag) {
    __shared__ bf16_t sQ[64 * 128];
    __shared__ bf16_t sKA[64 * 128];   // sK (swizzled) in phase 1; sA [64][72] in phase 2
    __shared__ bf16_t sVT[128 * 72];
    __shared__ float sgw[128];
    bf16_t* sA = sKA;
    int bx = blockIdx.x;
    int n = bx & 31, h = (bx >> 5) & 15, b = bx >> 9;
    int tid = threadIdx.x, lane = tid & 63, wid = tid >> 6;
    int l15 = lane & 15, quad = lane >> 4;
    float log2g = log2f(1.f - exp2f(-5.f - (float)h));

    if (tid < 128) {
        sgw[tid] = (*flag) ? (float)((const bf16_t*)gwp)[tid] : ((const float*)gwp)[tid];
    }
#pragma unroll
    for (int l = 0; l < 4; ++l) {
        int idx = tid + 256 * l;
        int t = idx >> 4, k = idx & 15, d8 = k * 8;
        size_t gb = (((size_t)((b * 2048 + n * 64 + t) * 16 + h)) << 7) + d8;
        int qk_off = t * 128 + ((k ^ (t & 7)) * 8);       // chunk swizzle key (t&7)
        *(bf16x8*)&sQ[qk_off] = *(const bf16x8*)&Q[gb];
        *(bf16x8*)&sKA[qk_off] = *(const bf16x8*)&Kc[gb];
        bf16x8 vv = *(const bf16x8*)&Vc[gb];
        int swc = (((t >> 3) ^ (k & 7)) * 8) + (t & 7);   // sVT swizzle key
#pragma unroll
        for (int m = 0; m < 8; ++m) sVT[(d8 + m) * 72 + swc] = vv[m];
    }
    __syncthreads();

    // ---- phase 1: A = q k^T (64x64), decay mask
    int t0 = wid * 16;
    int x7 = l15 & 7;
    floatx4 accA[4] = {};
#pragma unroll
    for (int kk = 0; kk < 4; ++kk) {
        int qd = kk * 4 + quad;
        bf16x8 aq = *(const bf16x8*)&sQ[(t0 + l15) * 128 + (qd ^ x7) * 8];
#pragma unroll
        for (int j = 0; j < 4; ++j) {
            bf16x8 bk = *(const bf16x8*)&sKA[(j * 16 + l15) * 128 + (qd ^ x7) * 8];
            accA[j] = MFMA16(aq, bk, accA[j]);
        }
    }
    __syncthreads();                      // sK consumed; sA may now overwrite it
#pragma unroll
    for (int j = 0; j < 4; ++j)
#pragma unroll
        for (int r = 0; r < 4; ++r) {
            int t = t0 + quad * 4 + r;
            int s = j * 16 + l15;
            int rel = t - s;
            float v = (rel >= 0) ? accA[j][r] * exp2f((float)rel * log2g) : 0.f;
            sA[t * 72 + s] = (bf16_t)v;
        }
    __syncthreads();

    // ---- phase 2: o = A v + (q*cross) S
    floatx4 acc[8] = {};
#pragma unroll
    for (int kk = 0; kk < 2; ++kk) {          // K = 64 (s)
        int s0 = kk * 32 + quad * 8;
        int qs = kk * 4 + quad;
        bf16x8 aa = *(const bf16x8*)&sA[(t0 + l15) * 72 + s0];
#pragma unroll
        for (int j = 0; j < 8; ++j) {
            int key = (2 * j + (l15 >> 3)) & 7;
            bf16x8 bv = *(const bf16x8*)&sVT[(j * 16 + l15) * 72 + (qs ^ key) * 8];
            acc[j] = MFMA16(aa, bv, acc[j]);
        }
    }
    size_t sb = (size_t)bx * 16384;
    float crossf = exp2f((float)(t0 + l15 + 1) * log2g);
#pragma unroll
    for (int kk = 0; kk < 4; ++kk) {          // K = 128 (d)
        int qd = kk * 4 + quad;
        bf16x8 aq = *(const bf16x8*)&sQ[(t0 + l15) * 128 + (qd ^ x7) * 8];
        bf16x8 aqs;
#pragma unroll
        for (int m = 0; m < 8; ++m) aqs[m] = (bf16_t)((float)aq[m] * crossf);
        int d0 = kk * 32 + quad * 8;
#pragma unroll
        for (int j = 0; j < 8; ++j) {
            bf16x8 bs = *(const bf16x8*)&St[sb + (size_t)(j * 16 + l15) * 128 + d0];
            acc[j] = MFMA16(aqs, bs, acc[j]);
        }
    }

    // ---- epilogue: gated RMSNorm per row t
#pragma unroll
    for (int r = 0; r < 4; ++r) {
        float ss = 0.f;
#pragma unroll
        for (int j = 0; j < 8; ++j) ss += acc[j][r] * acc[j][r];
        ss += __shfl_xor(ss, 1);
        ss += __shfl_xor(ss, 2);
        ss += __shfl_xor(ss, 4);
        ss += __shfl_xor(ss, 8);
        float rms = rsqrtf(ss * (1.f / 128.f) + 1e-5f);
        int t = t0 + quad * 4 + r;
        size_t gb = ((size_t)((b * 2048 + n * 64 + t) * 16 + h)) << 7;
#pragma unroll
        for (int j = 0; j < 8; ++j) {
            int e = j * 16 + l15;
            float g_ = (float)G[gb + e];
            float sw = g_ / (1.f + __expf(-g_));
            OG[gb + e] = (bf16_t)(acc[j][r] * rms * sgw[e] * sw);
        }
    }
}

// ---------------------------------------------------------------------------
extern "C" void kernel_launch(void* const* d_in, const int* in_sizes, int n_in,
                              void* d_out, int out_size, void* d_ws, size_t ws_size,
                              hipStream_t stream) {
    char* ws = (char*)d_ws;
    const size_t WBYTES = 2048ull * 2048 * 2;   // 8 MiB per bf16 weight
    const size_t ABYTES = 4096ull * 2048 * 2;   // 16 MiB per bf16 activation
    int* flag = (int*)ws;
    char* base = ws + 256;
    bf16_t* xb = (bf16_t*)base;
    bf16_t* WT[5];
    for (int i = 0; i < 5; ++i) WT[i] = (bf16_t*)(base + ABYTES + i * WBYTES);
    char* act = base + ABYTES + 5 * WBYTES;
    bf16_t* qb = (bf16_t*)(act + 0 * ABYTES);
    bf16_t* kb = (bf16_t*)(act + 1 * ABYTES);
    bf16_t* vb = (bf16_t*)(act + 2 * ABYTES);
    bf16_t* gb = (bf16_t*)(act + 3 * ABYTES);
    bf16_t* og = (bf16_t*)(act + 4 * ABYTES);
    bf16_t* US = (bf16_t*)(act + 5 * ABYTES);  // 32 MiB

    // 0. detect dtype (flag=1 -> bf16 inputs)
    detect_dtype_kernel<<<1, 256, 0, stream>>>((const unsigned int*)d_in[1], flag);

    // 1. fused prep: transpose 5 weights (z<5) + canonicalize x (z=5)
    TPtrs tp;
    tp.src[0] = d_in[1]; tp.src[1] = d_in[2]; tp.src[2] = d_in[3];
    tp.src[3] = d_in[4]; tp.src[4] = d_in[6];
    for (int i = 0; i < 5; ++i) tp.dst[i] = WT[i];
    prep_kernel<<<dim3(32, 32, 6), 256, 0, stream>>>(tp, d_in[0], xb, flag);

    // 2. fused QKVG projections with fused RoPE (z=0: q scaled, z=1: k)
    //    256x256 tile, 512 threads, ring-2 / 2-blocks-per-CU pipeline
    GPtrs gp;
    gp.Bt[0] = WT[0]; gp.Bt[1] = WT[1]; gp.Bt[2] = WT[2]; gp.Bt[3] = WT[3];
    gp.C[0] = qb; gp.C[1] = kb; gp.C[2] = vb; gp.C[3] = gb;
    gemm_bt<<<dim3(8, 16, 4), 512, 0, stream>>>(xb, gp, 2048);

    // 3. retention
    chunk_state_kernel<<<1024, 256, 0, stream>>>(kb, vb, US);
    scan_kernel<<<256, 256, 0, stream>>>(US);
    chunk_out_kernel<<<1024, 256, 0, stream>>>(qb, kb, vb, gb, d_in[5], US, og, flag);

    // 4. output projection (dtype-dynamic store)
    gemm_bt_dyn<<<dim3(16, 32, 1), 256, 0, stream>>>(og, WT[4], d_out, 2048, flag);
}

// Round 8
// 396.967 us; speedup vs baseline: 5.9655x; 5.9655x over previous
//
#include <hip/hip_runtime.h>

typedef __bf16 bf16_t;
typedef __bf16 bf16x8 __attribute__((ext_vector_type(8)));
typedef float floatx4 __attribute__((ext_vector_type(4)));

#define MFMA16(a, b, c) __builtin_amdgcn_mfma_f32_16x16x32_bf16(a, b, c, 0, 0, 0)

#define AS1 __attribute__((address_space(1)))
#define AS3 __attribute__((address_space(3)))

// async 16B global -> LDS (lane i lands at ldsbase + i*16; ldsbase wave-uniform)
__device__ __forceinline__ void gload_lds16(const bf16_t* g, bf16_t* l) {
    __builtin_amdgcn_global_load_lds((const AS1 unsigned int*)g,
                                     (AS3 unsigned int*)l, 16, 0, 0);
}

struct TPtrs { const void* src[5]; bf16_t* dst[5]; };
struct GPtrs { const bf16_t* Bt[4]; bf16_t* C[4]; };

// ---------------------------------------------------------------------------
// Detect input dtype on-device (flag=1 -> bf16 inputs; measured: fp32 world).
// ---------------------------------------------------------------------------
__global__ __launch_bounds__(256) void detect_dtype_kernel(const unsigned int* W,
                                                           int* flag) {
    int tid = threadIdx.x;
    int cnt = 0;
    for (int i = tid; i < 4096; i += 256) {
        unsigned int fb = (W[i] & 0xFFFFu) << 16;
        float v = __uint_as_float(fb);
        float a = fabsf(v);
        if (a > 1e-5f && a < 4.f) cnt++;
    }
    __shared__ int s[256];
    s[tid] = cnt;
    __syncthreads();
    for (int st = 128; st > 0; st >>= 1) {
        if (tid < st) s[tid] += s[tid + st];
        __syncthreads();
    }
    if (tid == 0) *flag = (s[0] > 2048) ? 1 : 0;
}

// ---------------------------------------------------------------------------
// Fused prep: z<5 -> transpose weight z (2048x2048 -> bf16, dst[n][k]);
// z==5 -> canonicalize x -> bf16 (8,388,608 elems).  grid (32,32,6).
// ---------------------------------------------------------------------------
__global__ __launch_bounds__(256) void prep_kernel(TPtrs p,
                                                   const void* __restrict__ xsrc,
                                                   bf16_t* __restrict__ xb,
                                                   const int* __restrict__ flag) {
    int z = blockIdx.z;
    int tid = threadIdx.x;
    int isbf = *flag;
    if (z == 5) {
        size_t blin = (size_t)blockIdx.y * 32 + blockIdx.x;   // [0,1024)
        size_t i0 = (blin * 256 + tid) * 8;
#pragma unroll
        for (int l = 0; l < 4; ++l) {
            size_t idx = i0 + (size_t)l * 2097152;            // 1024*256*8
            bf16x8 o;
            if (isbf) {
                o = *(const bf16x8*)((const bf16_t*)xsrc + idx);
            } else {
                const float* s = (const float*)xsrc + idx;
                float4 a = *(const float4*)s;
                float4 b = *(const float4*)(s + 4);
                o[0] = (bf16_t)a.x; o[1] = (bf16_t)a.y; o[2] = (bf16_t)a.z; o[3] = (bf16_t)a.w;
                o[4] = (bf16_t)b.x; o[5] = (bf16_t)b.y; o[6] = (bf16_t)b.z; o[7] = (bf16_t)b.w;
            }
            *(bf16x8*)(xb + idx) = o;
        }
        return;
    }
    __shared__ bf16_t tile[64][72];  // +8 pad
    bf16_t* dst = p.dst[z];
    int bx = blockIdx.x, by = blockIdx.y;
#pragma unroll
    for (int l = 0; l < 2; ++l) {
        int idx = tid + 256 * l;          // 512 x 8 elems = 64 rows x 64 cols
        int r = idx >> 3, c8 = (idx & 7) * 8;
        bf16x8 o;
        if (isbf) {
            const bf16_t* src = (const bf16_t*)p.src[z];
            o = *(const bf16x8*)&src[(size_t)(by * 64 + r) * 2048 + bx * 64 + c8];
        } else {
            const float* src = (const float*)p.src[z];
            const float* sp = &src[(size_t)(by * 64 + r) * 2048 + bx * 64 + c8];
            float4 a = *(const float4*)sp;
            float4 b = *(const float4*)(sp + 4);
            o[0] = (bf16_t)a.x; o[1] = (bf16_t)a.y; o[2] = (bf16_t)a.z; o[3] = (bf16_t)a.w;
            o[4] = (bf16_t)b.x; o[5] = (bf16_t)b.y; o[6] = (bf16_t)b.z; o[7] = (bf16_t)b.w;
        }
        *(bf16x8*)&tile[r][c8] = o;
    }
    __syncthreads();
#pragma unroll
    for (int l = 0; l < 2; ++l) {
        int idx = tid + 256 * l;
        int r = idx >> 3, c8 = (idx & 7) * 8;
        bf16x8 o;
#pragma unroll
        for (int m = 0; m < 8; ++m) o[m] = tile[c8 + m][r];
        *(bf16x8*)&dst[(size_t)(bx * 64 + r) * 2048 + by * 64 + c8] = o;
    }
}

// ---------------------------------------------------------------------------
// QKVG GEMM with fused RoPE.  C[M,N] = A[M,K] @ Bt[N,K]^T, bf16 out.
// 256x256 tile, 512 threads (8 waves 2x4), BK=32, 4-deep LDS ring buffer,
// reg-prefetch + 1 barrier/tile (round-3 validated structure, 139.4 us).
//
// ROUND-8: consolidation.  Rounds 4-7 established: (a) no intra-wave
// schedule variant beats round-3 at 2 waves/SIMD lockstep (8-phase,
// sched_barrier pins, full-tile reg dbuf all null/worse); (b) 2 blocks/CU
// is ARITHMETICALLY unreachable (acc alone = 128 regs/wave; 4 waves/SIMD
// caps the unified file at 128 -> round-7's spill catastrophe).  So:
// round-3 exact, plus ONE new mechanism-distinct lever:
//
// XCD-chunked block remap (T1): default dispatch puts the 8 x-siblings
// sharing an A-panel (same y,z) on 8 DIFFERENT XCD L2s (lin%8 == x).
// Bijective remap  x=(lin>>3)&7, yz=(lin&7)*8+(lin>>6)  co-locates all
// 8 siblings on one XCD -> A panel fetched once per L2 instead of 8x.
// Watch FETCH_SIZE (147 MB -> ~100-120 MB if mechanism engages).
//
// Safety (unchanged since round 2): lgkmcnt(0) folded into the per-tile
// waitcnt before the barrier => no wave holds pending ds_reads against
// any buffer past a barrier; staging overwrites a buffer only >= 1 tile
// after its last reader's drain (ring 4 >= skew 1 + prefetch 3).
// Counted vmcnt(8) steady state; tail 8 -> 4 -> 0.
// ---------------------------------------------------------------------------
__global__ __launch_bounds__(512, 2) void gemm_bt(const bf16_t* __restrict__ A,
                                                  GPtrs p, int K) {
    __shared__ bf16_t sm[4][2][8192];   // [buf][A/B][256*32] = 128 KiB
    // ---- XCD-chunked bijective remap of (x, y, z)
    int lin = (int)blockIdx.x + ((int)blockIdx.y << 3) + ((int)blockIdx.z << 7);
    int bx = (lin >> 3) & 7;
    int yz = (lin & 7) * 8 + (lin >> 6);
    int by = yz & 15;
    int z = yz >> 4;
    bf16_t* __restrict__ C = p.C[z];
    const int N = 2048;
    int tid = threadIdx.x, lane = tid & 63, wid = tid >> 6;
    int l15 = lane & 15, quad = lane >> 4;
    int wm = wid >> 2, wn = wid & 3;                 // 2 x 4 waves
    int m0 = by * 256, n0 = bx * 256;

    // staging: wave wid covers rows [wid*16,+16) of each 128-row half;
    // inverse XOR on the SOURCE k-granule so swizzled reads recover data.
    int kg = ((lane & 3) ^ ((lane >> 3) & 3)) * 8;
    size_t aoff = (size_t)(wid * 16 + (lane >> 2)) * K + kg;
    const bf16_t* Au = A + (size_t)m0 * K;           // uniform base
    const bf16_t* Bu = p.Bt[z] + (size_t)n0 * K;

    // fragment read swizzle: granule = quad ^ ((row>>1)&3), row = R0+l15.
    int gph = (quad ^ ((l15 >> 1) & 3)) * 8;

    // B-fragment rows: pair rotary cols (d, d+64) of one head into adjacent j
    int jr[4];
#pragma unroll
    for (int j = 0; j < 4; ++j)
        jr[j] = (wn >> 1) * 128 + (j & 1) * 64 + (wn & 1) * 32 + (j >> 1) * 16 + l15;

    const int NT = K >> 5;                           // 32-wide K tiles (64)

    // ---- prologue: stage tiles 0,1,2 (12 loads/wave)
#pragma unroll
    for (int u = 0; u < 3; ++u) {
        const bf16_t* sa = Au + (size_t)u * 32 + aoff;
        const bf16_t* sb = Bu + (size_t)u * 32 + aoff;
        bf16_t* da = &sm[u][0][wid * 512];
        bf16_t* db = &sm[u][1][wid * 512];
        gload_lds16(sa, da);
        gload_lds16(sa + (size_t)128 * K, da + 4096);
        gload_lds16(sb, db);
        gload_lds16(sb + (size_t)128 * K, db + 4096);
    }
    asm volatile("s_waitcnt vmcnt(8) lgkmcnt(0)" ::: "memory");  // tile 0 landed
    __builtin_amdgcn_s_barrier();
    asm volatile("" ::: "memory");

    bf16x8 afA[8], afB[8], b01[2], b23[2];
    floatx4 acc[8][4] = {};

    // initial fragment reads: af(0) -> afA, b01(0)
    {
        const bf16_t* bA0 = &sm[0][0][0];
        const bf16_t* bB0 = &sm[0][1][0];
#pragma unroll
        for (int i = 0; i < 8; ++i)
            afA[i] = *(const bf16x8*)&bA0[(wm * 128 + i * 16 + l15) * 32 + gph];
        b01[0] = *(const bf16x8*)&bB0[jr[0] * 32 + gph];
        b01[1] = *(const bf16x8*)&bB0[jr[1] * 32 + gph];
    }

#define TILE_STEP(T, AFU, AFL)                                                 \
    {                                                                          \
        const int t_ = (T);                                                    \
        const bf16_t* bB_ = &sm[t_ & 3][1][0];                                 \
        /* ---- phase A: stage A(t+3) | read bv23(t) | MFMA j01 */             \
        if (t_ + 3 < NT) {                                                     \
            const bf16_t* s_ = Au + (size_t)(t_ + 3) * 32 + aoff;              \
            bf16_t* d_ = &sm[(t_ + 3) & 3][0][wid * 512];                      \
            gload_lds16(s_, d_);                                               \
            gload_lds16(s_ + (size_t)128 * K, d_ + 4096);                      \
        }                                                                      \
        b23[0] = *(const bf16x8*)&bB_[jr[2] * 32 + gph];                       \
        b23[1] = *(const bf16x8*)&bB_[jr[3] * 32 + gph];                       \
        __builtin_amdgcn_s_setprio(1);                                         \
        _Pragma("unroll")                                                      \
        for (int i = 0; i < 8; ++i) {                                          \
            acc[i][0] = MFMA16(AFU[i], b01[0], acc[i][0]);                     \
            acc[i][1] = MFMA16(AFU[i], b01[1], acc[i][1]);                     \
        }                                                                      \
        __builtin_amdgcn_s_setprio(0);                                         \
        /* ---- phase B: stage B(t+3) | wait+barrier | prefetch frags(t+1) */  \
        /*      | MFMA j23 (prefetch drains under it) */                       \
        if (t_ + 3 < NT) {                                                     \
            const bf16_t* s_ = Bu + (size_t)(t_ + 3) * 32 + aoff;              \
            bf16_t* d_ = &sm[(t_ + 3) & 3][1][wid * 512];                      \
            gload_lds16(s_, d_);                                               \
            gload_lds16(s_ + (size_t)128 * K, d_ + 4096);                      \
        }                                                                      \
        if (t_ + 3 < NT)                                                       \
            asm volatile("s_waitcnt vmcnt(8) lgkmcnt(0)" ::: "memory");        \
        else if (t_ + 3 == NT)                                                 \
            asm volatile("s_waitcnt vmcnt(4) lgkmcnt(0)" ::: "memory");        \
        else                                                                   \
            asm volatile("s_waitcnt vmcnt(0) lgkmcnt(0)" ::: "memory");        \
        __builtin_amdgcn_s_barrier();                                          \
        asm volatile("" ::: "memory");                                         \
        if (t_ + 1 < NT) {                                                     \
            const bf16_t* nA_ = &sm[(t_ + 1) & 3][0][0];                       \
            const bf16_t* nB_ = &sm[(t_ + 1) & 3][1][0];                       \
            _Pragma("unroll")                                                  \
            for (int i = 0; i < 8; ++i)                                        \
                AFL[i] = *(const bf16x8*)&nA_[(wm * 128 + i * 16 + l15) * 32 + gph]; \
            b01[0] = *(const bf16x8*)&nB_[jr[0] * 32 + gph];                   \
            b01[1] = *(const bf16x8*)&nB_[jr[1] * 32 + gph];                   \
        }                                                                      \
        __builtin_amdgcn_s_setprio(1);                                         \
        _Pragma("unroll")                                                      \
        for (int i = 0; i < 8; ++i) {                                          \
            acc[i][2] = MFMA16(AFU[i], b23[0], acc[i][2]);                     \
            acc[i][3] = MFMA16(AFU[i], b23[1], acc[i][3]);                     \
        }                                                                      \
        __builtin_amdgcn_s_setprio(0);                                         \
    }

    for (int it = 0; it < NT; it += 2) {
        TILE_STEP(it, afA, afB)
        TILE_STEP(it + 1, afB, afA)
    }
#undef TILE_STEP

    if (z < 2) {
        // ---- fused RoPE epilogue (q: scaled, k: unscaled)
        float scale = (z == 0) ? 0.08838834764831845f : 1.0f;
#pragma unroll
        for (int jj = 0; jj < 2; ++jj) {
            int d = (wn & 1) * 32 + jj * 16 + l15;               // head-local [0,64)
            float inv = exp2f(-(float)d * (13.287712379549449f / 64.f));
            int cb = n0 + (wn >> 1) * 128 + d;                   // x1 column
#pragma unroll
            for (int i = 0; i < 8; ++i)
#pragma unroll
                for (int r = 0; r < 4; ++r) {
                    int row = m0 + wm * 128 + i * 16 + quad * 4 + r;
                    float ang = (float)(row & 2047) * inv;
                    float sn, cs;
                    __sincosf(ang, &sn, &cs);
                    float x1 = acc[i][2 * jj][r], x2 = acc[i][2 * jj + 1][r];
                    size_t ro = (size_t)row * N + cb;
                    C[ro]      = (bf16_t)((x1 * cs - x2 * sn) * scale);
                    C[ro + 64] = (bf16_t)((x2 * cs + x1 * sn) * scale);
                }
        }
    } else {
#pragma unroll
        for (int i = 0; i < 8; ++i)
#pragma unroll
            for (int j = 0; j < 4; ++j)
#pragma unroll
                for (int r = 0; r < 4; ++r) {
                    int row = m0 + wm * 128 + i * 16 + quad * 4 + r;
                    int col = n0 + jr[j];
                    C[(size_t)row * N + col] = (bf16_t)acc[i][j][r];
                }
    }
}

// ---------------------------------------------------------------------------
// Final GEMM: out dtype dynamic (flag=1 -> bf16, else fp32).  saddr staging.
// ---------------------------------------------------------------------------
__global__ __launch_bounds__(256) void gemm_bt_dyn(const bf16_t* __restrict__ A,
                                                   const bf16_t* __restrict__ Bt,
                                                   void* __restrict__ C, int K,
                                                   const int* __restrict__ flag) {
    __shared__ bf16_t sA[128 * 64];
    __shared__ bf16_t sB[128 * 64];
    const int N = 2048;
    int tid = threadIdx.x, lane = tid & 63, wid = tid >> 6;
    int l15 = lane & 15, quad = lane >> 4;
    int wm = wid >> 1, wn = wid & 1;
    int m0 = blockIdx.y * 128, n0 = blockIdx.x * 128;
    int isbf = *flag;

    int srow = tid >> 3;
    unsigned aoff = (unsigned)(srow * K + (((tid & 7) ^ (srow & 7)) * 8));
    const bf16_t* Au = A + (size_t)m0 * K;
    const bf16_t* Bu = Bt + (size_t)n0 * K;
    bf16_t* la = &sA[(size_t)(wid * 64) * 8];
    bf16_t* lb = &sB[(size_t)(wid * 64) * 8];
    const int rstep = 32 * K;
    int x7 = l15 & 7;

    floatx4 acc[4][4] = {};
    for (int kk = 0; kk < K; kk += 64) {
#pragma unroll
        for (int l = 0; l < 4; ++l)
            gload_lds16(Au + l * rstep + aoff, la + l * 2048);
#pragma unroll
        for (int l = 0; l < 4; ++l)
            gload_lds16(Bu + l * rstep + aoff, lb + l * 2048);
        Au += 64;
        Bu += 64;
        __syncthreads();
#pragma unroll
        for (int k2 = 0; k2 < 2; ++k2) {
            int koff = ((k2 * 4 + quad) ^ x7) * 8;
            bf16x8 af[4], bfv[4];
#pragma unroll
            for (int i = 0; i < 4; ++i)
                af[i] = *(const bf16x8*)&sA[(wm * 64 + i * 16 + l15) * 64 + koff];
#pragma unroll
            for (int j = 0; j < 4; ++j)
                bfv[j] = *(const bf16x8*)&sB[(wn * 64 + j * 16 + l15) * 64 + koff];
#pragma unroll
            for (int i = 0; i < 4; ++i)
#pragma unroll
                for (int j = 0; j < 4; ++j)
                    acc[i][j] = MFMA16(af[i], bfv[j], acc[i][j]);
        }
        __syncthreads();
    }
#pragma unroll
    for (int i = 0; i < 4; ++i)
#pragma unroll
        for (int j = 0; j < 4; ++j)
#pragma unroll
            for (int r = 0; r < 4; ++r) {
                int row = m0 + wm * 64 + i * 16 + quad * 4 + r;
                int col = n0 + wn * 64 + j * 16 + l15;
                if (isbf) ((bf16_t*)C)[(size_t)row * N + col] = (bf16_t)acc[i][j][r];
                else      ((float*)C)[(size_t)row * N + col] = acc[i][j][r];
            }
}

// ---------------------------------------------------------------------------
// Pass A: Ut[e][d] = sum_t v[t][e] * gamma^(63-t) * k[t][d].  grid 1024.
// Column-chunk XOR swizzle on transposed staging (conflict-reduced).
// ---------------------------------------------------------------------------
__global__ __launch_bounds__(256) void chunk_state_kernel(const bf16_t* __restrict__ Kc,
                                                          const bf16_t* __restrict__ Vc,
                                                          bf16_t* __restrict__ U) {
    __shared__ bf16_t sKT[128 * 72];
    __shared__ bf16_t sVT[128 * 72];
    int bx = blockIdx.x;
    int n = bx & 31, h = (bx >> 5) & 15, b = bx >> 9;
    int tid = threadIdx.x, lane = tid & 63, wid = tid >> 6;
    int l15 = lane & 15, quad = lane >> 4;
    int wm = wid >> 1, wn = wid & 1;
    float log2g = log2f(1.f - exp2f(-5.f - (float)h));

#pragma unroll
    for (int l = 0; l < 4; ++l) {
        int idx = tid + 256 * l;          // 1024 = 64 rows x 16 vec8
        int t = idx >> 4, k = idx & 15, d8 = k * 8;
        size_t gb = (((size_t)((b * 2048 + n * 64 + t) * 16 + h)) << 7) + d8;
        bf16x8 kv = *(const bf16x8*)&Kc[gb];
        bf16x8 vv = *(const bf16x8*)&Vc[gb];
        float kdec = exp2f((float)(63 - t) * log2g);
        int swc = (((t >> 3) ^ (k & 7)) * 8) + (t & 7);
#pragma unroll
        for (int m = 0; m < 8; ++m) {
            sKT[(d8 + m) * 72 + swc] = (bf16_t)((float)kv[m] * kdec);
            sVT[(d8 + m) * 72 + swc] = vv[m];
        }
    }
    __syncthreads();

    floatx4 acc[4][4] = {};
#pragma unroll
    for (int k2 = 0; k2 < 2; ++k2) {
        int q = k2 * 4 + quad;
        bf16x8 af[4], bfv[4];
#pragma unroll
        for (int i = 0; i < 4; ++i) {
            int key = (2 * i + (l15 >> 3)) & 7;
            af[i] = *(const bf16x8*)&sVT[(wm * 64 + i * 16 + l15) * 72 + (q ^ key) * 8];
        }
#pragma unroll
        for (int j = 0; j < 4; ++j) {
            int key = (2 * j + (l15 >> 3)) & 7;
            bfv[j] = *(const bf16x8*)&sKT[(wn * 64 + j * 16 + l15) * 72 + (q ^ key) * 8];
        }
#pragma unroll
        for (int i = 0; i < 4; ++i)
#pragma unroll
            for (int j = 0; j < 4; ++j) acc[i][j] = MFMA16(af[i], bfv[j], acc[i][j]);
    }
    size_t ub = (size_t)bx * 16384;
#pragma unroll
    for (int i = 0; i < 4; ++i)
#pragma unroll
        for (int j = 0; j < 4; ++j)
#pragma unroll
            for (int r = 0; r < 4; ++r) {
                int e = wm * 64 + i * 16 + quad * 4 + r;
                int d = wn * 64 + j * 16 + l15;
                U[ub + (size_t)e * 128 + d] = (bf16_t)acc[i][j][r];
            }
}

// ---------------------------------------------------------------------------
// Pass B: in-place scan  St[n] = state before chunk n (transposed layout).
// ---------------------------------------------------------------------------
__global__ __launch_bounds__(256) void scan_kernel(bf16_t* __restrict__ US) {
    int bx = blockIdx.x;
    int bh = bx >> 3, slice = bx & 7;
    int h = bh & 15;
    float log2g = log2f(1.f - exp2f(-5.f - (float)h));
    float gC = exp2f(64.f * log2g);
    size_t base = (size_t)bh * 32 * 16384 + (size_t)slice * 2048 + (size_t)threadIdx.x * 8;
    float acc[8] = {};
#pragma unroll 4
    for (int n = 0; n < 32; ++n) {
        size_t o = base + (size_t)n * 16384;
        bf16x8 u = *(const bf16x8*)&US[o];
        bf16x8 s;
#pragma unroll
        for (int m = 0; m < 8; ++m) s[m] = (bf16_t)acc[m];
        *(bf16x8*)&US[o] = s;
#pragma unroll
        for (int m = 0; m < 8; ++m) acc[m] = gC * acc[m] + (float)u[m];
    }
}

// ---------------------------------------------------------------------------
// Pass C: chunk output + gated RMSNorm.  grid 1024.
// sQ/sK: [64][128] chunk XOR swizzle key (t&7); sVT: [128][72] swizzled;
// sA overlays sK (dead after phase 1) -> ~51 KB LDS -> 3 blocks/CU.
// ---------------------------------------------------------------------------
__global__ __launch_bounds__(256) void chunk_out_kernel(
    const bf16_t* __restrict__ Q, const bf16_t* __restrict__ Kc,
    const bf16_t* __restrict__ Vc, const bf16_t* __restrict__ G,
    const void* __restrict__ gwp, const bf16_t* __restrict__ St,
    bf16_t* __restrict__ OG, const int* __restrict__ flag) {
    __shared__ bf16_t sQ[64 * 128];
    __shared__ bf16_t sKA[64 * 128];   // sK (swizzled) in phase 1; sA [64][72] in phase 2
    __shared__ bf16_t sVT[128 * 72];
    __shared__ float sgw[128];
    bf16_t* sA = sKA;
    int bx = blockIdx.x;
    int n = bx & 31, h = (bx >> 5) & 15, b = bx >> 9;
    int tid = threadIdx.x, lane = tid & 63, wid = tid >> 6;
    int l15 = lane & 15, quad = lane >> 4;
    float log2g = log2f(1.f - exp2f(-5.f - (float)h));

    if (tid < 128) {
        sgw[tid] = (*flag) ? (float)((const bf16_t*)gwp)[tid] : ((const float*)gwp)[tid];
    }
#pragma unroll
    for (int l = 0; l < 4; ++l) {
        int idx = tid + 256 * l;
        int t = idx >> 4, k = idx & 15, d8 = k * 8;
        size_t gb = (((size_t)((b * 2048 + n * 64 + t) * 16 + h)) << 7) + d8;
        int qk_off = t * 128 + ((k ^ (t & 7)) * 8);       // chunk swizzle key (t&7)
        *(bf16x8*)&sQ[qk_off] = *(const bf16x8*)&Q[gb];
        *(bf16x8*)&sKA[qk_off] = *(const bf16x8*)&Kc[gb];
        bf16x8 vv = *(const bf16x8*)&Vc[gb];
        int swc = (((t >> 3) ^ (k & 7)) * 8) + (t & 7);   // sVT swizzle key
#pragma unroll
        for (int m = 0; m < 8; ++m) sVT[(d8 + m) * 72 + swc] = vv[m];
    }
    __syncthreads();

    // ---- phase 1: A = q k^T (64x64), decay mask
    int t0 = wid * 16;
    int x7 = l15 & 7;
    floatx4 accA[4] = {};
#pragma unroll
    for (int kk = 0; kk < 4; ++kk) {
        int qd = kk * 4 + quad;
        bf16x8 aq = *(const bf16x8*)&sQ[(t0 + l15) * 128 + (qd ^ x7) * 8];
#pragma unroll
        for (int j = 0; j < 4; ++j) {
            bf16x8 bk = *(const bf16x8*)&sKA[(j * 16 + l15) * 128 + (qd ^ x7) * 8];
            accA[j] = MFMA16(aq, bk, accA[j]);
        }
    }
    __syncthreads();                      // sK consumed; sA may now overwrite it
#pragma unroll
    for (int j = 0; j < 4; ++j)
#pragma unroll
        for (int r = 0; r < 4; ++r) {
            int t = t0 + quad * 4 + r;
            int s = j * 16 + l15;
            int rel = t - s;
            float v = (rel >= 0) ? accA[j][r] * exp2f((float)rel * log2g) : 0.f;
            sA[t * 72 + s] = (bf16_t)v;
        }
    __syncthreads();

    // ---- phase 2: o = A v + (q*cross) S
    floatx4 acc[8] = {};
#pragma unroll
    for (int kk = 0; kk < 2; ++kk) {          // K = 64 (s)
        int s0 = kk * 32 + quad * 8;
        int qs = kk * 4 + quad;
        bf16x8 aa = *(const bf16x8*)&sA[(t0 + l15) * 72 + s0];
#pragma unroll
        for (int j = 0; j < 8; ++j) {
            int key = (2 * j + (l15 >> 3)) & 7;
            bf16x8 bv = *(const bf16x8*)&sVT[(j * 16 + l15) * 72 + (qs ^ key) * 8];
            acc[j] = MFMA16(aa, bv, acc[j]);
        }
    }
    size_t sb = (size_t)bx * 16384;
    float crossf = exp2f((float)(t0 + l15 + 1) * log2g);
#pragma unroll
    for (int kk = 0; kk < 4; ++kk) {          // K = 128 (d)
        int qd = kk * 4 + quad;
        bf16x8 aq = *(const bf16x8*)&sQ[(t0 + l15) * 128 + (qd ^ x7) * 8];
        bf16x8 aqs;
#pragma unroll
        for (int m = 0; m < 8; ++m) aqs[m] = (bf16_t)((float)aq[m] * crossf);
        int d0 = kk * 32 + quad * 8;
#pragma unroll
        for (int j = 0; j < 8; ++j) {
            bf16x8 bs = *(const bf16x8*)&St[sb + (size_t)(j * 16 + l15) * 128 + d0];
            acc[j] = MFMA16(aqs, bs, acc[j]);
        }
    }

    // ---- epilogue: gated RMSNorm per row t
#pragma unroll
    for (int r = 0; r < 4; ++r) {
        float ss = 0.f;
#pragma unroll
        for (int j = 0; j < 8; ++j) ss += acc[j][r] * acc[j][r];
        ss += __shfl_xor(ss, 1);
        ss += __shfl_xor(ss, 2);
        ss += __shfl_xor(ss, 4);
        ss += __shfl_xor(ss, 8);
        float rms = rsqrtf(ss * (1.f / 128.f) + 1e-5f);
        int t = t0 + quad * 4 + r;
        size_t gb = ((size_t)((b * 2048 + n * 64 + t) * 16 + h)) << 7;
#pragma unroll
        for (int j = 0; j < 8; ++j) {
            int e = j * 16 + l15;
            float g_ = (float)G[gb + e];
            float sw = g_ / (1.f + __expf(-g_));
            OG[gb + e] = (bf16_t)(acc[j][r] * rms * sgw[e] * sw);
        }
    }
}

// ---------------------------------------------------------------------------
extern "C" void kernel_launch(void* const* d_in, const int* in_sizes, int n_in,
                              void* d_out, int out_size, void* d_ws, size_t ws_size,
                              hipStream_t stream) {
    char* ws = (char*)d_ws;
    const size_t WBYTES = 2048ull * 2048 * 2;   // 8 MiB per bf16 weight
    const size_t ABYTES = 4096ull * 2048 * 2;   // 16 MiB per bf16 activation
    int* flag = (int*)ws;
    char* base = ws + 256;
    bf16_t* xb = (bf16_t*)base;
    bf16_t* WT[5];
    for (int i = 0; i < 5; ++i) WT[i] = (bf16_t*)(base + ABYTES + i * WBYTES);
    char* act = base + ABYTES + 5 * WBYTES;
    bf16_t* qb = (bf16_t*)(act + 0 * ABYTES);
    bf16_t* kb = (bf16_t*)(act + 1 * ABYTES);
    bf16_t* vb = (bf16_t*)(act + 2 * ABYTES);
    bf16_t* gb = (bf16_t*)(act + 3 * ABYTES);
    bf16_t* og = (bf16_t*)(act + 4 * ABYTES);
    bf16_t* US = (bf16_t*)(act + 5 * ABYTES);  // 32 MiB

    // 0. detect dtype (flag=1 -> bf16 inputs)
    detect_dtype_kernel<<<1, 256, 0, stream>>>((const unsigned int*)d_in[1], flag);

    // 1. fused prep: transpose 5 weights (z<5) + canonicalize x (z=5)
    TPtrs tp;
    tp.src[0] = d_in[1]; tp.src[1] = d_in[2]; tp.src[2] = d_in[3];
    tp.src[3] = d_in[4]; tp.src[4] = d_in[6];
    for (int i = 0; i < 5; ++i) tp.dst[i] = WT[i];
    prep_kernel<<<dim3(32, 32, 6), 256, 0, stream>>>(tp, d_in[0], xb, flag);

    // 2. fused QKVG projections with fused RoPE (z=0: q scaled, z=1: k)
    //    256x256 tile, 512 threads, round-3 pipeline + XCD-chunked remap
    GPtrs gp;
    gp.Bt[0] = WT[0]; gp.Bt[1] = WT[1]; gp.Bt[2] = WT[2]; gp.Bt[3] = WT[3];
    gp.C[0] = qb; gp.C[1] = kb; gp.C[2] = vb; gp.C[3] = gb;
    gemm_bt<<<dim3(8, 16, 4), 512, 0, stream>>>(xb, gp, 2048);

    // 3. retention
    chunk_state_kernel<<<1024, 256, 0, stream>>>(kb, vb, US);
    scan_kernel<<<256, 256, 0, stream>>>(US);
    chunk_out_kernel<<<1024, 256, 0, stream>>>(qb, kb, vb, gb, d_in[5], US, og, flag);

    // 4. output projection (dtype-dynamic store)
    gemm_bt_dyn<<<dim3(16, 32, 1), 256, 0, stream>>>(og, WT[4], d_out, 2048, flag);
}